// Round 3
// baseline (6267.526 us; speedup 1.0000x reference)
//
#include <hip/hip_runtime.h>

// ---------------------------------------------------------------------------
// UNet DeltaNet forward, MI355X/gfx950 — round 3.
// fp32 inputs/outputs; q/k/v/o intermediates stored bf16 (fp32 accumulation).
// Workspace use ~203 MB (round-2's 386 MB overran ws_size -> fault).
// Shapes: B=8, C=768, L=4096, n_heads=12, D=64, CHUNK=64, BH=96.
//
//  1) k_beta : beta[b][h][l] = sigmoid(sum_c x[b][c][l] * Wb[c][h])  (fp32)
//  2) k_proj : q/k = l2norm(silu(t@W)), v = silu(t@Wv) -> bf16 [b][h][l][d]
//  3) k_fused: per (b,h): chunkwise delta rule, S[64][64] fp32 in LDS;
//              per chunk: As=strict(beta_i*KK^T); rhs=beta*(V-K*S) fused with
//              oacc=Q*S; forward-substitute U; masked QK^T; O -> bf16 o[b][l][c];
//              S += K^T U.   64 KB LDS.
//  4) k_final: out[b][c][l] = x[b][c][l] + (o @ Wo)[b][l][c]   (fp32 out)
// ---------------------------------------------------------------------------

#define B_  8
#define C_  768
#define L_  4096
#define NH_ 12
#define D_  64
#define NC_ 64
#define BH_ 96

typedef unsigned short ushort_t;
typedef float f32x4 __attribute__((ext_vector_type(4)));
typedef unsigned short u16x4 __attribute__((ext_vector_type(4)));
typedef unsigned short u16x8 __attribute__((ext_vector_type(8)));

__device__ __forceinline__ float b2f(ushort_t u) {
  union { unsigned u; float f; } x; x.u = ((unsigned)u) << 16; return x.f;
}
__device__ __forceinline__ ushort_t f2b(float f) {
  union { float f; unsigned u; } x; x.f = f;
  unsigned r = (x.u + 0x7FFFu + ((x.u >> 16) & 1u)) >> 16;
  return (ushort_t)r;
}

// ---------------------------------------------------------------------------
// beta = sigmoid(x^T @ Wb); grid (L/256, B), 256 thr.
__global__ __launch_bounds__(256) void k_beta(
    const float* __restrict__ x, const float* __restrict__ Wb,
    float* __restrict__ beta) {
  __shared__ float wb[C_ * NH_];   // 36 KB
  int tid = threadIdx.x;
  for (int i = tid; i < C_ * NH_; i += 256) wb[i] = Wb[i];
  __syncthreads();
  int b = blockIdx.y;
  int l = blockIdx.x * 256 + tid;
  f32x4 a0 = {0.f, 0.f, 0.f, 0.f}, a1 = a0, a2 = a0;
  const float* xb = x + (size_t)b * C_ * L_ + l;
  for (int c = 0; c < C_; ++c) {
    float xv = xb[(size_t)c * L_];
    const f32x4* wr = (const f32x4*)&wb[c * NH_];
    a0 += xv * wr[0]; a1 += xv * wr[1]; a2 += xv * wr[2];
  }
  float* bp = beta + (size_t)b * NH_ * L_ + l;
  #pragma unroll
  for (int h = 0; h < 4; ++h) {
    bp[(size_t)h * L_]       = 1.f / (1.f + expf(-a0[h]));
    bp[(size_t)(h + 4) * L_] = 1.f / (1.f + expf(-a1[h]));
    bp[(size_t)(h + 8) * L_] = 1.f / (1.f + expf(-a2[h]));
  }
}

// ---------------------------------------------------------------------------
// Projection GEMM: out[b][h][l][d] = epi( sum_c x[b][c][l] * W[c][h*64+d] )
// 128x64 C-tile, thread = 8x4. grid (L/128, NH, B), 256 thr. Output bf16.
__global__ __launch_bounds__(256) void k_proj(
    const float* __restrict__ x, const float* __restrict__ W,
    ushort_t* __restrict__ outp, int norm) {
  __shared__ float As[32 * 128];  // 16 KB  As[kk][row]
  __shared__ float Bs[32 * 64];   //  8 KB  Bs[kk][col]
  int tid = threadIdx.x;
  int b = blockIdx.z, h = blockIdx.y;
  int l0 = blockIdx.x * 128;
  int ti = tid >> 4, tj = tid & 15;
  float acc[8][4];
  #pragma unroll
  for (int r = 0; r < 8; ++r)
    #pragma unroll
    for (int s = 0; s < 4; ++s) acc[r][s] = 0.f;
  const float* xb = x + (size_t)b * C_ * L_ + l0;
  const float* wb = W + h * 64;
  for (int kb = 0; kb < C_; kb += 32) {
    #pragma unroll
    for (int it = 0; it < 4; ++it) {
      int e = tid + it * 256;          // 1024 f32x4
      int kk = e >> 5, lq = e & 31;
      *(f32x4*)&As[kk * 128 + lq * 4] =
          *(const f32x4*)(xb + (size_t)(kb + kk) * L_ + lq * 4);
    }
    #pragma unroll
    for (int it = 0; it < 2; ++it) {
      int e = tid + it * 256;          // 512 f32x4
      int kk = e >> 4, nq = e & 15;
      *(f32x4*)&Bs[kk * 64 + nq * 4] =
          *(const f32x4*)(wb + (size_t)(kb + kk) * C_ + nq * 4);
    }
    __syncthreads();
    #pragma unroll 8
    for (int kk = 0; kk < 32; ++kk) {
      f32x4 a0 = *(const f32x4*)&As[kk * 128 + ti * 8];
      f32x4 a1 = *(const f32x4*)&As[kk * 128 + ti * 8 + 4];
      f32x4 bv = *(const f32x4*)&Bs[kk * 64 + tj * 4];
      #pragma unroll
      for (int r = 0; r < 4; ++r)
        #pragma unroll
        for (int s = 0; s < 4; ++s) {
          acc[r][s]     += a0[r] * bv[s];
          acc[r + 4][s] += a1[r] * bv[s];
        }
    }
    __syncthreads();
  }
  // epilogue: silu (+ optional per-head l2norm over d)
  #pragma unroll
  for (int r = 0; r < 8; ++r)
    #pragma unroll
    for (int s = 0; s < 4; ++s) {
      float xv = acc[r][s];
      acc[r][s] = xv / (1.f + expf(-xv));
    }
  if (norm) {
    #pragma unroll
    for (int r = 0; r < 8; ++r) {
      float ss = acc[r][0]*acc[r][0] + acc[r][1]*acc[r][1]
               + acc[r][2]*acc[r][2] + acc[r][3]*acc[r][3];
      ss += __shfl_xor(ss, 1); ss += __shfl_xor(ss, 2);
      ss += __shfl_xor(ss, 4); ss += __shfl_xor(ss, 8);
      float rs = rsqrtf(ss + 1e-6f);
      #pragma unroll
      for (int s = 0; s < 4; ++s) acc[r][s] *= rs;
    }
  }
  ushort_t* ob = outp + (((size_t)b * NH_ + h) * L_ + l0 + ti * 8) * 64 + tj * 4;
  #pragma unroll
  for (int r = 0; r < 8; ++r) {
    u16x4 pv = {f2b(acc[r][0]), f2b(acc[r][1]), f2b(acc[r][2]), f2b(acc[r][3])};
    *(u16x4*)(ob + (size_t)r * 64) = pv;
  }
}

// ---------------------------------------------------------------------------
// Fused chunkwise delta rule. grid (BH), 256 thr, 64 KB LDS.
// q/k/v bf16 in; o bf16 out; all math fp32; S fp32 in LDS.
__global__ __launch_bounds__(256) void k_fused(
    const ushort_t* __restrict__ qg, const ushort_t* __restrict__ kg,
    const ushort_t* __restrict__ vg, const float* __restrict__ betag,
    ushort_t* __restrict__ og) {
  __shared__ float Kc[64 * 64];   // 16 KB  K chunk [i][d]
  __shared__ float Sm[64 * 64];   // 16 KB  state S [d][e]
  __shared__ float As[64 * 64];   // 16 KB  strict beta*KK^T, then masked QK^T
  __shared__ float Xs[64 * 64];   // 16 KB  rhs -> U [i][e]
  int tid = threadIdx.x;
  int bh = blockIdx.x;
  int ti = tid >> 4, tj = tid & 15;
  for (int i = tid; i < 4096; i += 256) Sm[i] = 0.f;
  const ushort_t* qb = qg + (size_t)bh * L_ * 64;
  const ushort_t* kb = kg + (size_t)bh * L_ * 64;
  const ushort_t* vb = vg + (size_t)bh * L_ * 64;
  const float* bb = betag + (size_t)bh * L_;
  int b = bh / NH_, h = bh % NH_;
  ushort_t* ob = og + (size_t)b * L_ * C_ + h * 64;
  __syncthreads();
  for (int nc = 0; nc < NC_; ++nc) {
    size_t cb = (size_t)nc * 64 * 64;
    // ---- stage K chunk (bf16 -> fp32 LDS)
    #pragma unroll
    for (int it = 0; it < 2; ++it) {
      int e = tid + it * 256;          // 512 u16x8 = 4096 elements
      u16x8 kv8 = *(const u16x8*)(kb + cb + (size_t)e * 8);
      f32x4 lo = {b2f(kv8[0]), b2f(kv8[1]), b2f(kv8[2]), b2f(kv8[3])};
      f32x4 hi = {b2f(kv8[4]), b2f(kv8[5]), b2f(kv8[6]), b2f(kv8[7])};
      *(f32x4*)&Kc[e * 8]     = lo;
      *(f32x4*)&Kc[e * 8 + 4] = hi;
    }
    __syncthreads();
    // ---- As = strict_tril(beta_i * K K^T)
    {
      float kk[4][4];
      #pragma unroll
      for (int r = 0; r < 4; ++r)
        #pragma unroll
        for (int s = 0; s < 4; ++s) kk[r][s] = 0.f;
      for (int d = 0; d < 64; d += 4) {
        f32x4 ka[4], kj[4];
        #pragma unroll
        for (int r = 0; r < 4; ++r) ka[r] = *(const f32x4*)&Kc[(ti*4+r)*64 + d];
        #pragma unroll
        for (int s = 0; s < 4; ++s) kj[s] = *(const f32x4*)&Kc[(tj*4+s)*64 + d];
        #pragma unroll
        for (int r = 0; r < 4; ++r)
          #pragma unroll
          for (int s = 0; s < 4; ++s)
            #pragma unroll
            for (int q = 0; q < 4; ++q) kk[r][s] += ka[r][q] * kj[s][q];
      }
      #pragma unroll
      for (int r = 0; r < 4; ++r) {
        int i = ti * 4 + r;
        float bi = bb[nc * 64 + i];
        #pragma unroll
        for (int s = 0; s < 4; ++s) {
          int j = tj * 4 + s;
          As[i * 64 + j] = (j < i) ? bi * kk[r][s] : 0.f;
        }
      }
    }
    __syncthreads();
    // ---- rhs = beta_i*(V - K*S) -> Xs ; oacc = Q*S (kept in regs)
    float oacc[4][4];
    {
      float racc[4][4];
      #pragma unroll
      for (int r = 0; r < 4; ++r)
        #pragma unroll
        for (int s = 0; s < 4; ++s) { racc[r][s] = 0.f; oacc[r][s] = 0.f; }
      for (int d = 0; d < 64; d += 4) {
        f32x4 sv[4];
        #pragma unroll
        for (int q = 0; q < 4; ++q) sv[q] = *(const f32x4*)&Sm[(d+q)*64 + tj*4];
        #pragma unroll
        for (int r = 0; r < 4; ++r) {
          int i = ti * 4 + r;
          f32x4 kv = *(const f32x4*)&Kc[i * 64 + d];
          u16x4 qv4 = *(const u16x4*)(qb + cb + (size_t)i * 64 + d);
          f32x4 qv = {b2f(qv4[0]), b2f(qv4[1]), b2f(qv4[2]), b2f(qv4[3])};
          #pragma unroll
          for (int q = 0; q < 4; ++q)
            #pragma unroll
            for (int s = 0; s < 4; ++s) {
              racc[r][s] += kv[q] * sv[q][s];
              oacc[r][s] += qv[q] * sv[q][s];
            }
        }
      }
      #pragma unroll
      for (int r = 0; r < 4; ++r) {
        int i = ti * 4 + r;
        float bi = bb[nc * 64 + i];
        u16x4 vv4 = *(const u16x4*)(vb + cb + (size_t)i * 64 + tj * 4);
        #pragma unroll
        for (int s = 0; s < 4; ++s)
          Xs[i * 64 + tj * 4 + s] = bi * (b2f(vv4[s]) - racc[r][s]);
      }
    }
    __syncthreads();
    // ---- forward substitution: (I+As) U = rhs, 64 independent columns
    if (tid < 64) {
      int col = tid;
      for (int i = 1; i < 64; ++i) {
        float xi = Xs[i * 64 + col];
        for (int j = 0; j < i; j += 4) {   // As zero on/above diag
          f32x4 a4 = *(const f32x4*)&As[i * 64 + j];
          xi -= a4[0] * Xs[(j + 0) * 64 + col] + a4[1] * Xs[(j + 1) * 64 + col]
              + a4[2] * Xs[(j + 2) * 64 + col] + a4[3] * Xs[(j + 3) * 64 + col];
        }
        Xs[i * 64 + col] = xi;
      }
    }
    __syncthreads();
    // ---- masked QK^T into As (As dead after solve)
    {
      float qk[4][4];
      #pragma unroll
      for (int r = 0; r < 4; ++r)
        #pragma unroll
        for (int s = 0; s < 4; ++s) qk[r][s] = 0.f;
      for (int d = 0; d < 64; d += 4) {
        f32x4 qa[4], kj[4];
        #pragma unroll
        for (int r = 0; r < 4; ++r) {
          u16x4 qv4 = *(const u16x4*)(qb + cb + (size_t)(ti*4+r) * 64 + d);
          f32x4 qv = {b2f(qv4[0]), b2f(qv4[1]), b2f(qv4[2]), b2f(qv4[3])};
          qa[r] = qv;
        }
        #pragma unroll
        for (int s = 0; s < 4; ++s) kj[s] = *(const f32x4*)&Kc[(tj*4+s)*64 + d];
        #pragma unroll
        for (int r = 0; r < 4; ++r)
          #pragma unroll
          for (int s = 0; s < 4; ++s)
            #pragma unroll
            for (int q = 0; q < 4; ++q) qk[r][s] += qa[r][q] * kj[s][q];
      }
      #pragma unroll
      for (int r = 0; r < 4; ++r) {
        int i = ti * 4 + r;
        #pragma unroll
        for (int s = 0; s < 4; ++s) {
          int j = tj * 4 + s;
          As[i * 64 + j] = (j <= i) ? qk[r][s] : 0.f;
        }
      }
    }
    __syncthreads();
    // ---- O = oacc + Qk*U -> global bf16 ; S += K^T * U
    {
      for (int j = 0; j < 64; j += 4) {
        f32x4 uv[4];
        #pragma unroll
        for (int q = 0; q < 4; ++q) uv[q] = *(const f32x4*)&Xs[(j+q)*64 + tj*4];
        #pragma unroll
        for (int r = 0; r < 4; ++r) {
          f32x4 av = *(const f32x4*)&As[(ti*4+r)*64 + j];
          #pragma unroll
          for (int q = 0; q < 4; ++q)
            #pragma unroll
            for (int s = 0; s < 4; ++s) oacc[r][s] += av[q] * uv[q][s];
        }
      }
      #pragma unroll
      for (int r = 0; r < 4; ++r) {
        u16x4 pv = {f2b(oacc[r][0]), f2b(oacc[r][1]),
                    f2b(oacc[r][2]), f2b(oacc[r][3])};
        *(u16x4*)(ob + (size_t)(nc * 64 + ti * 4 + r) * C_ + tj * 4) = pv;
      }
      float sacc[4][4];
      #pragma unroll
      for (int r = 0; r < 4; ++r)
        #pragma unroll
        for (int s = 0; s < 4; ++s) sacc[r][s] = 0.f;
      for (int i = 0; i < 64; ++i) {
        f32x4 kv = *(const f32x4*)&Kc[i * 64 + ti * 4];
        f32x4 uv = *(const f32x4*)&Xs[i * 64 + tj * 4];
        #pragma unroll
        for (int r = 0; r < 4; ++r)
          #pragma unroll
          for (int s = 0; s < 4; ++s) sacc[r][s] += kv[r] * uv[s];
      }
      #pragma unroll
      for (int r = 0; r < 4; ++r)
        #pragma unroll
        for (int s = 0; s < 4; ++s)
          Sm[(ti * 4 + r) * 64 + tj * 4 + s] += sacc[r][s];
    }
    __syncthreads();
  }
}

// ---------------------------------------------------------------------------
// Final GEMM + residual: out[b][c][l] = x[b][c][l] + sum_k o[b][l][k]*Wo[k][c]
// o is bf16 [b][l][c]; out fp32. grid (L/128, C/64, B), 256 thr.
__global__ __launch_bounds__(256) void k_final(
    const ushort_t* __restrict__ o, const float* __restrict__ Wo,
    const float* __restrict__ x, float* __restrict__ outp) {
  __shared__ float As[32 * 132];  // As[kk][row], stride 132 (conflict pad)
  __shared__ float Bs[32 * 64];
  int tid = threadIdx.x;
  int b = blockIdx.z;
  int n0 = blockIdx.y * 64;
  int l0 = blockIdx.x * 128;
  int ti = tid >> 4, tj = tid & 15;
  float acc[8][4];
  #pragma unroll
  for (int r = 0; r < 8; ++r)
    #pragma unroll
    for (int s = 0; s < 4; ++s) acc[r][s] = 0.f;
  const ushort_t* obase = o + ((size_t)b * L_ + l0) * C_;
  const float* wb = Wo + n0;
  for (int kb = 0; kb < C_; kb += 32) {
    #pragma unroll
    for (int it = 0; it < 4; ++it) {
      int e = tid + it * 256;          // row = e>>3 (0..127), c4 = e&7
      int row = e >> 3, c4 = e & 7;
      u16x4 lv = *(const u16x4*)(obase + (size_t)row * C_ + kb + c4 * 4);
      #pragma unroll
      for (int q = 0; q < 4; ++q) As[(c4 * 4 + q) * 132 + row] = b2f(lv[q]);
    }
    #pragma unroll
    for (int it = 0; it < 2; ++it) {
      int e = tid + it * 256;
      int kk = e >> 4, nq = e & 15;
      *(f32x4*)&Bs[kk * 64 + nq * 4] =
          *(const f32x4*)(wb + (size_t)(kb + kk) * C_ + nq * 4);
    }
    __syncthreads();
    #pragma unroll 8
    for (int kk = 0; kk < 32; ++kk) {
      f32x4 a0 = *(const f32x4*)&As[kk * 132 + ti * 8];
      f32x4 a1 = *(const f32x4*)&As[kk * 132 + ti * 8 + 4];
      f32x4 bv = *(const f32x4*)&Bs[kk * 64 + tj * 4];
      #pragma unroll
      for (int r = 0; r < 4; ++r)
        #pragma unroll
        for (int s = 0; s < 4; ++s) {
          acc[r][s]     += a0[r] * bv[s];
          acc[r + 4][s] += a1[r] * bv[s];
        }
    }
    __syncthreads();
  }
  #pragma unroll
  for (int s = 0; s < 4; ++s) {
    int n = n0 + tj * 4 + s;
    size_t base = ((size_t)b * C_ + n) * L_ + l0 + ti * 8;
    f32x4 xlo = *(const f32x4*)(x + base);
    f32x4 xhi = *(const f32x4*)(x + base + 4);
    f32x4 lo = {acc[0][s] + xlo[0], acc[1][s] + xlo[1],
                acc[2][s] + xlo[2], acc[3][s] + xlo[3]};
    f32x4 hi = {acc[4][s] + xhi[0], acc[5][s] + xhi[1],
                acc[6][s] + xhi[2], acc[7][s] + xhi[3]};
    *(f32x4*)(outp + base) = lo;
    *(f32x4*)(outp + base + 4) = hi;
  }
}

// ---------------------------------------------------------------------------
extern "C" void kernel_launch(void* const* d_in, const int* in_sizes, int n_in,
                              void* d_out, int out_size, void* d_ws, size_t ws_size,
                              hipStream_t stream) {
  (void)in_sizes; (void)n_in; (void)out_size; (void)ws_size;
  const float* x  = (const float*)d_in[0];
  const float* Wq = (const float*)d_in[1];
  const float* Wk = (const float*)d_in[2];
  const float* Wv = (const float*)d_in[3];
  const float* Wb = (const float*)d_in[4];
  const float* Wo = (const float*)d_in[5];
  float* outp = (float*)d_out;

  const size_t NE = (size_t)B_ * NH_ * L_ * D_;   // 25,165,824 elements
  ushort_t* q    = (ushort_t*)d_ws;               // bf16, 50.3 MB
  ushort_t* kbuf = q + NE;                        // bf16, 50.3 MB
  ushort_t* v    = kbuf + NE;                     // bf16, 50.3 MB
  float*    beta = (float*)(v + NE);              // fp32,  1.6 MB
  ushort_t* o    = (ushort_t*)(beta + (size_t)B_ * NH_ * L_);  // bf16, 50.3 MB
  // total ws use ~203 MB (< round-1's known-good 308 MB)

  k_beta<<<dim3(L_ / 256, B_), 256, 0, stream>>>(x, Wb, beta);
  k_proj<<<dim3(L_ / 128, NH_, B_), 256, 0, stream>>>(x, Wq, q, 1);
  k_proj<<<dim3(L_ / 128, NH_, B_), 256, 0, stream>>>(x, Wk, kbuf, 1);
  k_proj<<<dim3(L_ / 128, NH_, B_), 256, 0, stream>>>(x, Wv, v, 0);
  k_fused<<<dim3(BH_), 256, 0, stream>>>(q, kbuf, v, beta, o);
  k_final<<<dim3(L_ / 128, C_ / 64, B_), 256, 0, stream>>>(o, Wo, x, outp);
}